// Round 8
// baseline (1226.089 us; speedup 1.0000x reference)
//
#include <hip/hip_runtime.h>
#include <math.h>

#define NEG_SLOPE 0.2f
#define DBINS 512

typedef short short8 __attribute__((ext_vector_type(8)));
typedef float float4v __attribute__((ext_vector_type(4)));
typedef _Float16 h8 __attribute__((ext_vector_type(8)));

__device__ __forceinline__ unsigned short f2bf(float f) {
    unsigned u = __float_as_uint(f);
    unsigned r = (u + 0x7fff + ((u >> 16) & 1)) >> 16;
    return (unsigned short)r;
}
__device__ __forceinline__ float bf2f(unsigned short h) {
    return __uint_as_float(((unsigned)h) << 16);
}
__device__ __forceinline__ unsigned short f2h(float f) {
    _Float16 t = (_Float16)f;
    return *(unsigned short*)&t;
}

// async global->LDS, 16B per lane. ldsptr must be wave-uniform; HW adds lane*16.
__device__ __forceinline__ void gload_lds16(const void* g, void* l) {
    __builtin_amdgcn_global_load_lds(
        (const __attribute__((address_space(1))) unsigned int*)g,
        (__attribute__((address_space(3))) unsigned int*)l, 16, 0, 0);
}

// ======================= CSR build (by dst) =======================

__global__ void count_kernel(const int* __restrict__ dst, int E, int* __restrict__ counts) {
    int i = blockIdx.x * blockDim.x + threadIdx.x;
    if (i < E) atomicAdd(&counts[dst[i]], 1);
}

__global__ void scan1_kernel(const int* __restrict__ in, int n, int* __restrict__ bsums) {
    __shared__ int sdata[256];
    int tid = threadIdx.x;
    int base = blockIdx.x * 1024 + tid * 4;
    int s = 0;
#pragma unroll
    for (int j = 0; j < 4; ++j) if (base + j < n) s += in[base + j];
    sdata[tid] = s; __syncthreads();
    for (int off = 128; off > 0; off >>= 1) {
        if (tid < off) sdata[tid] += sdata[tid + off];
        __syncthreads();
    }
    if (tid == 0) bsums[blockIdx.x] = sdata[0];
}

// parallel exclusive scan of nb (<=128) block sums
__global__ void scan2_kernel(int* bsums, int nb) {
    __shared__ int sd[128];
    int tid = threadIdx.x;
    int v = (tid < nb) ? bsums[tid] : 0;
    sd[tid] = v; __syncthreads();
    for (int off = 1; off < 128; off <<= 1) {
        int t = (tid >= off) ? sd[tid - off] : 0;
        __syncthreads();
        sd[tid] += t;
        __syncthreads();
    }
    if (tid < nb) bsums[tid] = sd[tid] - v;  // exclusive
}

__global__ void scan3_kernel(const int* __restrict__ in, int n, const int* __restrict__ bsums,
                             int* __restrict__ row_ptr, int* __restrict__ cursor, int E) {
    __shared__ int sdata[256];
    int tid = threadIdx.x;
    int base = blockIdx.x * 1024 + tid * 4;
    int v[4]; int s = 0;
#pragma unroll
    for (int j = 0; j < 4; ++j) { v[j] = (base + j < n) ? in[base + j] : 0; s += v[j]; }
    sdata[tid] = s; __syncthreads();
    for (int off = 1; off < 256; off <<= 1) {
        int t = (tid >= off) ? sdata[tid - off] : 0;
        __syncthreads();
        sdata[tid] += t;
        __syncthreads();
    }
    int excl = sdata[tid] - s;
    int run = bsums[blockIdx.x] + excl;
#pragma unroll
    for (int j = 0; j < 4; ++j) {
        if (base + j < n) { row_ptr[base + j] = run; cursor[base + j] = run; run += v[j]; }
    }
    if (blockIdx.x == 0 && tid == 0) row_ptr[n] = E;
}

__global__ void fill_kernel(const int* __restrict__ dst, const int* __restrict__ src, int E,
                            int* __restrict__ cursor, int* __restrict__ sperm) {
    int i = blockIdx.x * blockDim.x + threadIdx.x;
    if (i < E) {
        int p = atomicAdd(&cursor[dst[i]], 1);
        sperm[p] = src[i];
    }
}

// ======================= degree sort (counting sort, descending) =======================

__global__ void hist_kernel(const int* __restrict__ row_ptr, int n, int* __restrict__ hist) {
    int i = blockIdx.x * 256 + threadIdx.x;
    if (i < n) {
        int d = row_ptr[i + 1] - row_ptr[i];
        if (d > DBINS - 1) d = DBINS - 1;
        atomicAdd(&hist[d], 1);
    }
}

// descending-order exclusive offsets: hcur[b] = #nodes with deg > b
__global__ void hscan_kernel(const int* __restrict__ hist, int* __restrict__ hcur) {
    __shared__ int sd[DBINS];
    int tid = threadIdx.x;          // 512 threads
    int rb = DBINS - 1 - tid;
    int v = hist[rb];
    sd[tid] = v; __syncthreads();
    for (int off = 1; off < DBINS; off <<= 1) {
        int t = (tid >= off) ? sd[tid - off] : 0;
        __syncthreads();
        sd[tid] += t;
        __syncthreads();
    }
    hcur[rb] = sd[tid] - v;
}

__global__ void order_kernel(const int* __restrict__ row_ptr, int n,
                             int* __restrict__ hcur, int* __restrict__ order) {
    int i = blockIdx.x * 256 + threadIdx.x;
    if (i < n) {
        int d = row_ptr[i + 1] - row_ptr[i];
        if (d > DBINS - 1) d = DBINS - 1;
        int p = atomicAdd(&hcur[d], 1);
        order[p] = i;
    }
}

// ======================= prep: W transposes + waSD dots + x->bf16, one dispatch =======================

__global__ __launch_bounds__(256) void prep_kernel(
    const float* __restrict__ W0, const float* __restrict__ W1, const float* __restrict__ W2,
    const float* __restrict__ a0, const float* __restrict__ a1, const float* __restrict__ a2,
    unsigned short* __restrict__ WT0, unsigned short* __restrict__ WT1, unsigned short* __restrict__ WT2,
    unsigned short* __restrict__ wa0, unsigned short* __restrict__ wa1, unsigned short* __restrict__ wa2,
    const float* __restrict__ x, unsigned short* __restrict__ xbf, int xtotal) {
    int i = blockIdx.x * 256 + threadIdx.x;
    if (i < 32768) {                    // W0 [128][256] -> WT0 [256][128]
        int k = i >> 8, n = i & 255;
        WT0[n * 128 + k] = f2bf(W0[i]);
    } else if (i < 98304) {             // W1 [256][256] -> WT1 [256][256]
        int j = i - 32768;
        int k = j >> 8, n = j & 255;
        WT1[n * 256 + k] = f2bf(W1[j]);
    } else if (i < 114688) {            // W2 [256][64] -> WT2 [64][256]
        int j = i - 98304;
        int k = j >> 6, n = j & 63;
        WT2[n * 256 + k] = f2bf(W2[j]);
    } else if (i < 114688 + 2048) {     // wa0 [16][128]
        int t = i - 114688;
        int k = t >> 4, j8 = t & 15;
        float s = 0.f;
        if (j8 < 8) {
            int h = j8 & 3, off = (j8 >> 2) * 64;
            for (int d = 0; d < 64; ++d)
                s += W0[k * 256 + h * 64 + d] * a0[h * 128 + off + d];
        }
        wa0[j8 * 128 + k] = f2bf(s);
    } else if (i < 114688 + 2048 + 4096) {  // wa1 [16][256]
        int t = i - 114688 - 2048;
        int k = t >> 4, j8 = t & 15;
        float s = 0.f;
        if (j8 < 8) {
            int h = j8 & 3, off = (j8 >> 2) * 64;
            for (int d = 0; d < 64; ++d)
                s += W1[k * 256 + h * 64 + d] * a1[h * 128 + off + d];
        }
        wa1[j8 * 256 + k] = f2bf(s);
    } else if (i < 124928) {            // wa2 [16][256]
        int t = i - 114688 - 2048 - 4096;
        int k = t >> 4, j8 = t & 15;
        float s = 0.f;
        if (j8 < 2) {
            for (int d = 0; d < 64; ++d)
                s += W2[k * 64 + d] * a2[j8 * 64 + d];
        }
        wa2[j8 * 256 + k] = f2bf(s);
    } else {                            // x -> bf16
        int j = i - 124928;
        if (j < xtotal) xbf[j] = f2bf(x[j]);
    }
}

// ======================= fused MFMA GEMM + alpha-via-MFMA + fp16-emit =======================

template <int BN>
__global__ __launch_bounds__(256) void gemm_fused(
    const unsigned short* __restrict__ A, const unsigned short* __restrict__ WT,
    const unsigned short* __restrict__ waSDT,
    unsigned short* __restrict__ hf16,
    float* __restrict__ as_, float* __restrict__ ad_,
    int M, int K) {
    __shared__ unsigned short AL[128 * 32];
    __shared__ unsigned short BL[BN * 32];
    __shared__ unsigned short WaL[16 * 32];

    int t = threadIdx.x;
    int w = t >> 6, lane = t & 63;
    int q = lane >> 4, i16 = lane & 15;
    int rowBase = blockIdx.x * 128;
    int colBase = blockIdx.y * BN;

    constexpr int MT = (BN == 128) ? 4 : 2;
    int wrow = (BN == 128) ? (w >> 1) * 64 : w * 32;
    int wcol = (BN == 128) ? (w & 1) * 64 : 0;

    bool alphaBlk = (blockIdx.y == 0);
    bool alphaWave = alphaBlk && ((BN == 64) || ((w & 1) == 0));

    float4v acc[MT][4];
    float4v accA[MT];
#pragma unroll
    for (int mt = 0; mt < MT; ++mt) {
        accA[mt] = (float4v)(0.f);
#pragma unroll
        for (int nt = 0; nt < 4; ++nt) acc[mt][nt] = (float4v)(0.f);
    }

    int srow = t >> 2;          // 0..63
    int skq = (t & 3) * 8;      // k offset in shorts (16B chunks)

    for (int k0 = 0; k0 < K; k0 += 32) {
        gload_lds16(A + (size_t)(rowBase + srow) * K + k0 + skq, AL + w * 512);
        gload_lds16(A + (size_t)(rowBase + 64 + srow) * K + k0 + skq, AL + 2048 + w * 512);
        gload_lds16(WT + (size_t)(colBase + srow) * K + k0 + skq, BL + w * 512);
        if (BN == 128)
            gload_lds16(WT + (size_t)(colBase + 64 + srow) * K + k0 + skq, BL + 2048 + w * 512);
        if (alphaBlk && w == 0)
            gload_lds16(waSDT + (size_t)srow * K + k0 + skq, WaL);
        __syncthreads();

        short8 af[MT], bf[4];
#pragma unroll
        for (int mt = 0; mt < MT; ++mt)
            af[mt] = *(short8*)&AL[(wrow + mt * 16 + i16) * 32 + q * 8];
#pragma unroll
        for (int nt = 0; nt < 4; ++nt)
            bf[nt] = *(short8*)&BL[(wcol + nt * 16 + i16) * 32 + q * 8];
#pragma unroll
        for (int mt = 0; mt < MT; ++mt)
#pragma unroll
            for (int nt = 0; nt < 4; ++nt)
                acc[mt][nt] = __builtin_amdgcn_mfma_f32_16x16x32_bf16(af[mt], bf[nt], acc[mt][nt], 0, 0, 0);
        if (alphaWave) {
            short8 aw = *(short8*)&WaL[i16 * 32 + q * 8];
#pragma unroll
            for (int mt = 0; mt < MT; ++mt)
                accA[mt] = __builtin_amdgcn_mfma_f32_16x16x32_bf16(af[mt], aw, accA[mt], 0, 0, 0);
        }
        __syncthreads();
    }

    int cb0 = colBase + wcol;
#pragma unroll
    for (int mt = 0; mt < MT; ++mt)
#pragma unroll
        for (int r = 0; r < 4; ++r) {
            int grow = rowBase + wrow + mt * 16 + q * 4 + r;
            bool ok = grow < M;
            if (ok) {
#pragma unroll
                for (int nt = 0; nt < 4; ++nt) {
                    float v = acc[mt][nt][r];
                    if (BN == 128) hf16[(size_t)grow * 256 + cb0 + nt * 16 + i16] = f2h(v);
                    else           hf16[(size_t)grow * 64 + nt * 16 + i16] = f2h(v);
                }
                if (alphaWave) {
                    float av = accA[mt][r];
                    if (BN == 128) {
                        if (i16 < 4)      as_[grow * 4 + i16] = av;
                        else if (i16 < 8) ad_[grow * 4 + (i16 - 4)] = av;
                    } else {
                        if (i16 == 0)      as_[grow] = av;
                        else if (i16 == 1) ad_[grow] = av;
                    }
                }
            }
        }
}

// ======================= aggregate H=4, fp16 messages, single-pass softmax =======================
// degree-sorted: wave idx -> node = order[idx]; per-node math identical (bitwise).

__global__ __launch_bounds__(256) void aggregate4(
    const unsigned short* __restrict__ hf16, const int* __restrict__ row_ptr,
    const int* __restrict__ sperm, const float* __restrict__ as_, const float* __restrict__ ad_,
    const int* __restrict__ order,
    unsigned short* __restrict__ outB, int n) {
    int w = threadIdx.x >> 6, lane = threadIdx.x & 63;
    int idx = blockIdx.x * 4 + w;
    if (idx >= n) return;
    int node = order[idx];
    int beg = row_ptr[node], end = row_ptr[node + 1];
    int deg = end - beg;
    int myh = lane & 3;
    float ad_my = ad_[node * 4 + myh];

    int half = lane >> 5;     // edge parity this lane aggregates
    int dg = lane & 31;       // dim group: dims dg*8..dg*8+7
    int hh = dg >> 3;         // head of those dims
    float acc[8];
#pragma unroll
    for (int k = 0; k < 8; ++k) acc[k] = 0.f;
    float lsum = 0.f;         // unnormalized denom partial for head myh

    const char* hbase = (const char*)hf16;
    unsigned dgo = (unsigned)dg << 4;

    for (int el0 = 0; el0 < deg; el0 += 16) {
        int ne = deg - el0; if (ne > 16) ne = 16;
        int eSlot = lane >> 2;
        float att = 0.f; int sMy = 0;
        if (eSlot < ne) {
            sMy = sperm[beg + el0 + eSlot];
            float e = as_[sMy * 4 + myh] + ad_my;
            e = e > 0.f ? e : NEG_SLOPE * e;
            att = __expf(e);
        }
        lsum += att;

        int j = 0;
        for (; j + 8 <= ne; j += 8) {
            int sl0 = j + half, sl1 = j + 2 + half, sl2 = j + 4 + half, sl3 = j + 6 + half;
            float a0 = __shfl(att, sl0 * 4 + hh, 64);
            int   s0 = __shfl(sMy, sl0 * 4, 64);
            float a1 = __shfl(att, sl1 * 4 + hh, 64);
            int   s1 = __shfl(sMy, sl1 * 4, 64);
            float a2 = __shfl(att, sl2 * 4 + hh, 64);
            int   s2 = __shfl(sMy, sl2 * 4, 64);
            float a3 = __shfl(att, sl3 * 4 + hh, 64);
            int   s3 = __shfl(sMy, sl3 * 4, 64);
            h8 v0 = *(const h8*)(hbase + (((unsigned)s0 << 9) + dgo));
            h8 v1 = *(const h8*)(hbase + (((unsigned)s1 << 9) + dgo));
            h8 v2 = *(const h8*)(hbase + (((unsigned)s2 << 9) + dgo));
            h8 v3 = *(const h8*)(hbase + (((unsigned)s3 << 9) + dgo));
#pragma unroll
            for (int k = 0; k < 8; ++k) acc[k] += a0 * (float)v0[k];
#pragma unroll
            for (int k = 0; k < 8; ++k) acc[k] += a1 * (float)v1[k];
#pragma unroll
            for (int k = 0; k < 8; ++k) acc[k] += a2 * (float)v2[k];
#pragma unroll
            for (int k = 0; k < 8; ++k) acc[k] += a3 * (float)v3[k];
        }
        for (; j < ne; j += 2) {
            int sl = j + half;
            float a = __shfl(att, sl * 4 + hh, 64);
            int   s = __shfl(sMy, sl * 4, 64);
            h8 v = *(const h8*)(hbase + (((unsigned)s << 9) + dgo));
#pragma unroll
            for (int k = 0; k < 8; ++k) acc[k] += a * (float)v[k];
        }
    }

#pragma unroll
    for (int m = 4; m < 64; m <<= 1) lsum += __shfl_xor(lsum, m, 64);
    float inv = 1.f / (lsum + 1e-16f);
    float invh = __shfl(inv, hh, 64);

#pragma unroll
    for (int k = 0; k < 8; ++k) {
        acc[k] += __shfl_xor(acc[k], 32, 64);
        acc[k] *= invh;
    }

    if (half == 0) {
        short8 hv;
#pragma unroll
        for (int k = 0; k < 8; ++k) {
            float o = acc[k] > 0.f ? acc[k] : expm1f(acc[k]);
            hv[k] = (short)f2bf(o);
        }
        *(short8*)(outB + (size_t)node * 256 + dg * 8) = hv;
    }
}

// ======================= aggregate H=1, single-pass, fp32 out (graded) =======================

__global__ __launch_bounds__(256) void aggregate1(
    const unsigned short* __restrict__ hf16, const int* __restrict__ row_ptr,
    const int* __restrict__ sperm, const float* __restrict__ as_, const float* __restrict__ ad_,
    const int* __restrict__ order,
    float* __restrict__ out, int n) {
    int w = threadIdx.x >> 6, lane = threadIdx.x & 63;
    int idx = blockIdx.x * 4 + w;
    if (idx >= n) return;
    int node = order[idx];
    int beg = row_ptr[node], end = row_ptr[node + 1];
    int deg = end - beg;
    float ad_n = ad_[node];

    int eg = lane >> 3;
    int dg = lane & 7;
    float acc[8];
#pragma unroll
    for (int k = 0; k < 8; ++k) acc[k] = 0.f;
    float lsum = 0.f;

    const char* hbase = (const char*)hf16;
    unsigned dgo = (unsigned)dg << 4;

    for (int el0 = 0; el0 < deg; el0 += 64) {
        int ne = deg - el0; if (ne > 64) ne = 64;
        float att = 0.f; int sMy = 0;
        if (lane < ne) {
            sMy = sperm[beg + el0 + lane];
            float e = as_[sMy] + ad_n;
            e = e > 0.f ? e : NEG_SLOPE * e;
            att = __expf(e);
        }
        lsum += att;

        int j = 0;
        for (; j + 32 <= ne; j += 32) {
            int sl0 = j + eg, sl1 = j + 8 + eg, sl2 = j + 16 + eg, sl3 = j + 24 + eg;
            float a0 = __shfl(att, sl0, 64);
            int   s0 = __shfl(sMy, sl0, 64);
            float a1 = __shfl(att, sl1, 64);
            int   s1 = __shfl(sMy, sl1, 64);
            float a2 = __shfl(att, sl2, 64);
            int   s2 = __shfl(sMy, sl2, 64);
            float a3 = __shfl(att, sl3, 64);
            int   s3 = __shfl(sMy, sl3, 64);
            h8 v0 = *(const h8*)(hbase + (((unsigned)s0 << 7) + dgo));
            h8 v1 = *(const h8*)(hbase + (((unsigned)s1 << 7) + dgo));
            h8 v2 = *(const h8*)(hbase + (((unsigned)s2 << 7) + dgo));
            h8 v3 = *(const h8*)(hbase + (((unsigned)s3 << 7) + dgo));
#pragma unroll
            for (int k = 0; k < 8; ++k) acc[k] += a0 * (float)v0[k];
#pragma unroll
            for (int k = 0; k < 8; ++k) acc[k] += a1 * (float)v1[k];
#pragma unroll
            for (int k = 0; k < 8; ++k) acc[k] += a2 * (float)v2[k];
#pragma unroll
            for (int k = 0; k < 8; ++k) acc[k] += a3 * (float)v3[k];
        }
        for (; j < ne; j += 8) {
            int sl = j + eg;
            float a = __shfl(att, sl, 64);
            int   s = __shfl(sMy, sl, 64);
            h8 v = *(const h8*)(hbase + (((unsigned)s << 7) + dgo));
#pragma unroll
            for (int k = 0; k < 8; ++k) acc[k] += a * (float)v[k];
        }
    }

#pragma unroll
    for (int m = 1; m < 64; m <<= 1) lsum += __shfl_xor(lsum, m, 64);
    float inv = 1.f / (lsum + 1e-16f);

#pragma unroll
    for (int m = 8; m < 64; m <<= 1)
#pragma unroll
        for (int k = 0; k < 8; ++k) acc[k] += __shfl_xor(acc[k], m, 64);

    if (eg == 0) {
        float4 o0 = make_float4(acc[0] * inv, acc[1] * inv, acc[2] * inv, acc[3] * inv);
        float4 o1 = make_float4(acc[4] * inv, acc[5] * inv, acc[6] * inv, acc[7] * inv);
        *(float4*)(out + (size_t)node * 64 + dg * 8) = o0;
        *(float4*)(out + (size_t)node * 64 + dg * 8 + 4) = o1;
    }
}

// ======================= launch =======================

extern "C" void kernel_launch(void* const* d_in, const int* in_sizes, int n_in,
                              void* d_out, int out_size, void* d_ws, size_t ws_size,
                              hipStream_t stream) {
    const float* x  = (const float*)d_in[0];
    const int*   ei = (const int*)d_in[1];
    const float* W0 = (const float*)d_in[2];
    const float* a0 = (const float*)d_in[3];
    const float* W1 = (const float*)d_in[4];
    const float* a1 = (const float*)d_in[5];
    const float* W2 = (const float*)d_in[6];
    const float* a2 = (const float*)d_in[7];
    float* out = (float*)d_out;

    int N = in_sizes[0] / 128;
    int E = in_sizes[1] / 2;
    int Npad = (N + 127) & ~127;
    const int* srcp = ei;
    const int* dstp = ei + E;

    char* ws = (char*)d_ws;
    size_t off = 0;
    auto alloc = [&](size_t bytes) -> void* {
        void* p = ws + off;
        off += (bytes + 255) & ~(size_t)255;
        return p;
    };
    unsigned short* xbf  = (unsigned short*)alloc((size_t)Npad * 128 * 2);
    unsigned short* actB = (unsigned short*)alloc((size_t)Npad * 256 * 2);
    unsigned short* hf16 = (unsigned short*)alloc((size_t)Npad * 256 * 2);
    unsigned short* Cf16 = (unsigned short*)alloc((size_t)Npad * 64 * 2);
    float* as_    = (float*)alloc((size_t)N * 4 * 4);
    float* ad_    = (float*)alloc((size_t)N * 4 * 4);
    size_t counts_off = off;
    int*   counts = (int*)alloc((size_t)N * 4);
    int*   hist   = (int*)alloc((size_t)DBINS * 4);
    size_t hist_end = off;
    int*   hcur   = (int*)alloc((size_t)DBINS * 4);
    int*   order  = (int*)alloc((size_t)N * 4);
    int*   row_ptr= (int*)alloc((size_t)(N + 1) * 4);
    int*   cursor = (int*)alloc((size_t)N * 4);
    int*   sperm  = (int*)alloc((size_t)E * 4);
    unsigned short* WT0 = (unsigned short*)alloc((size_t)256 * 128 * 2);
    unsigned short* WT1 = (unsigned short*)alloc((size_t)256 * 256 * 2);
    unsigned short* WT2 = (unsigned short*)alloc((size_t)64 * 256 * 2);
    unsigned short* wa0 = (unsigned short*)alloc((size_t)16 * 128 * 2);
    unsigned short* wa1 = (unsigned short*)alloc((size_t)16 * 256 * 2);
    unsigned short* wa2 = (unsigned short*)alloc((size_t)16 * 256 * 2);
    int*   bsums  = (int*)alloc(4096);

    // ---- CSR by dst (+ zero hist in the same memset span) ----
    hipMemsetAsync(counts, 0, hist_end - counts_off, stream);
    int egrid = (E + 255) / 256;
    count_kernel<<<egrid, 256, 0, stream>>>(dstp, E, counts);
    int nb = (N + 1023) / 1024;
    scan1_kernel<<<nb, 256, 0, stream>>>(counts, N, bsums);
    scan2_kernel<<<1, 128, 0, stream>>>(bsums, nb);
    scan3_kernel<<<nb, 256, 0, stream>>>(counts, N, bsums, row_ptr, cursor, E);
    fill_kernel<<<egrid, 256, 0, stream>>>(dstp, srcp, E, cursor, sperm);

    // ---- degree sort (descending) ----
    int ngrid256 = (N + 255) / 256;
    hist_kernel<<<ngrid256, 256, 0, stream>>>(row_ptr, N, hist);
    hscan_kernel<<<1, DBINS, 0, stream>>>(hist, hcur);
    order_kernel<<<ngrid256, 256, 0, stream>>>(row_ptr, N, hcur, order);

    // ---- prep: W transposes + waSD + x->bf16, one dispatch ----
    int xtotal = N * 128;
    prep_kernel<<<(124928 + xtotal + 255) / 256, 256, 0, stream>>>(
        W0, W1, W2, a0, a1, a2, WT0, WT1, WT2, wa0, wa1, wa2, x, xbf, xtotal);

    int gemm_gx = Npad / 128;
    int ngrid4 = (N + 3) / 4;

    // ---- Layer 0 ----
    gemm_fused<128><<<dim3(gemm_gx, 2), 256, 0, stream>>>(xbf, WT0, wa0, hf16, as_, ad_, N, 128);
    aggregate4<<<ngrid4, 256, 0, stream>>>(hf16, row_ptr, sperm, as_, ad_, order, actB, N);

    // ---- Layer 1 ----
    gemm_fused<128><<<dim3(gemm_gx, 2), 256, 0, stream>>>(actB, WT1, wa1, hf16, as_, ad_, N, 256);
    aggregate4<<<ngrid4, 256, 0, stream>>>(hf16, row_ptr, sperm, as_, ad_, order, actB, N);

    // ---- Layer 2 ----
    gemm_fused<64><<<dim3(gemm_gx, 1), 256, 0, stream>>>(actB, WT2, wa2, Cf16, as_, ad_, N, 256);
    aggregate1<<<ngrid4, 256, 0, stream>>>(Cf16, row_ptr, sperm, as_, ad_, order, out, N);
}